// Round 8
// baseline (272.888 us; speedup 1.0000x reference)
//
#include <hip/hip_runtime.h>

// StackedGIN: L=3 layers of { agg = h + scatter_sum(h[src] -> dst);
//   h = relu( relu(agg@W1+B1) @ W2 + B2 ) }, then out = h@Wc + Bc.
// N=50000, E=800000, D=96, C=10.
//
// R1: float4 gather, unroll x4.  R2: wave-scan slot assignment.
// R3: MLP via bf16 MFMA.         R4: h/agg stored bf16 (gather halved).
// R5: prep fuse; classifier fused into layer-3 MLP epilogue.
// R6: plain-dispatch CSR build (coop grid.sync was 5x slower: cross-XCD
//     coherence tax on scatter phases).
// R7: agg fused INTO the MLP kernel: phase-1 gathers straight into A_lds
//     (aggbuf + 3 dispatches + 19MB/layer round-trip eliminated).
// ws layout: hbuf(N*96 bf16) | start(N) | cursor(N, reused as bf16
//            Wt[6][96][96] after fill) | deg(N) | counter(1) | csr(E)

#define TPB 256
#define LDA 104  // bf16 elems per LDS row: 96 + 8 pad

typedef __attribute__((ext_vector_type(8))) short bfrag8;
typedef __attribute__((ext_vector_type(8))) unsigned short u16x8;
typedef __attribute__((ext_vector_type(4))) float f32x4;

__device__ inline unsigned short f2bf(float x) {  // RNE f32 -> bf16 bits
  unsigned int u = __float_as_uint(x);
  unsigned int r = u + 0x7FFFu + ((u >> 16) & 1u);
  return (unsigned short)(r >> 16);
}
__device__ inline float bf2f(unsigned short u) {
  return __uint_as_float(((unsigned int)u) << 16);
}

__global__ __launch_bounds__(TPB) void hist_kernel(const int* __restrict__ dst,
                                                   int* __restrict__ deg, int E) {
  int e = blockIdx.x * TPB + threadIdx.x;
  if (e < E) atomicAdd(&deg[dst[e]], 1);
}

// start[i] = running sum of deg in wave-chunked order (order irrelevant).
__global__ __launch_bounds__(TPB) void assign_kernel(const int* __restrict__ deg,
                                                     int* __restrict__ start,
                                                     int* __restrict__ cursor,
                                                     int* __restrict__ counter, int n) {
  int i = blockIdx.x * TPB + threadIdx.x;
  int d = (i < n) ? deg[i] : 0;
  int lane = threadIdx.x & 63;
  int incl = d;
#pragma unroll
  for (int off = 1; off < 64; off <<= 1) {
    int v = __shfl_up(incl, off, 64);
    if (lane >= off) incl += v;
  }
  int waveTotal = __shfl(incl, 63, 64);
  int base = 0;
  if (lane == 63) base = atomicAdd(counter, waveTotal);
  base = __shfl(base, 63, 64);
  int st = base + incl - d;
  if (i < n) { start[i] = st; cursor[i] = st; }
}

// fill: 2 edges per thread, independent atomic->store chains.
__global__ __launch_bounds__(TPB) void fill_kernel(const int* __restrict__ src,
                                                   const int* __restrict__ dst,
                                                   int* __restrict__ cursor,
                                                   int* __restrict__ csr, int E) {
  int t = blockIdx.x * TPB + threadIdx.x;
  int e0 = 2 * t, e1 = 2 * t + 1;
  if (e1 < E) {
    int d0 = dst[e0], d1 = dst[e1];
    int s0 = src[e0], s1 = src[e1];
    int slot0 = atomicAdd(&cursor[d0], 1);
    int slot1 = atomicAdd(&cursor[d1], 1);
    csr[slot0] = s0;
    csr[slot1] = s1;
  } else if (e0 < E) {
    int d0 = dst[e0];
    int slot0 = atomicAdd(&cursor[d0], 1);
    csr[slot0] = src[e0];
  }
}

// prep: wt[l*2+which][n][k] = bf16(W[l][k][n]); hbuf = bf16(x).
__global__ __launch_bounds__(TPB) void prep_kernel(const float* __restrict__ W1,
                                                   const float* __restrict__ W2,
                                                   unsigned short* __restrict__ wt,
                                                   const float4* __restrict__ x4,
                                                   u16x8* __restrict__ h8, int total8) {
  int t = blockIdx.x * TPB + threadIdx.x;
  const int wjobs = 6 * 9216;
  if (t < wjobs) {
    int mat = t / 9216, idx = t - mat * 9216;
    int l = mat >> 1, which = mat & 1;
    int k = idx / 96, n = idx - k * 96;
    const float* src = (which ? W2 : W1) + (size_t)l * 9216;
    wt[(size_t)mat * 9216 + n * 96 + k] = f2bf(src[k * 96 + n]);
  } else {
    int u = t - wjobs;
    if (u < total8) {
      float4 a = x4[2 * u], b = x4[2 * u + 1];
      u16x8 o;
      o[0] = f2bf(a.x); o[1] = f2bf(a.y); o[2] = f2bf(a.z); o[3] = f2bf(a.w);
      o[4] = f2bf(b.x); o[5] = f2bf(b.y); o[6] = f2bf(b.z); o[7] = f2bf(b.w);
      h8[u] = o;
    }
  }
}

// Fused layer: phase 1 gathers agg (GIN aggregation) for 64 rows directly
// into A_lds (bf16); phases 2-3 run the 2-stage MFMA MLP. LAST also computes
// out = h@Wc + Bc in the epilogue (h never stored).
template <bool LAST>
__global__ __launch_bounds__(TPB) void mlp_fused_kernel(
    const u16x8* __restrict__ hin8, const int* __restrict__ start,
    const int* __restrict__ deg, const int* __restrict__ csr,
    const unsigned short* __restrict__ wt1, const unsigned short* __restrict__ wt2,
    const float* __restrict__ B1, const float* __restrict__ B2,
    unsigned short* __restrict__ out,
    const float* __restrict__ Wc, const float* __restrict__ Bc,
    float* __restrict__ outf, int nrows) {
  __shared__ unsigned short A_lds[64 * LDA];   // agg tile, later Z tile
  __shared__ unsigned short W1_lds[96 * LDA];
  __shared__ unsigned short W2_lds[96 * LDA];
  const int tid = threadIdx.x;
  const int row0 = blockIdx.x * 64;

  // stage Wt1, Wt2 (issue these tiny loads first)
  for (int t = tid; t < 2 * 1152; t += TPB) {
    int which = t / 1152, idx = t - which * 1152;
    int n = idx / 12, c8 = idx - n * 12;
    const unsigned short* src = (which ? wt2 : wt1) + n * 96 + 8 * c8;
    bfrag8 v = *reinterpret_cast<const bfrag8*>(src);
    unsigned short* dp = (which ? W2_lds : W1_lds) + n * LDA + 8 * c8;
    *reinterpret_cast<bfrag8*>(dp) = v;
  }

  // phase 1: gather agg[gr][c8] = h[gr][c8] + sum_j h[csr[j]][c8] -> A_lds
  for (int t = tid; t < 64 * 12; t += TPB) {
    int r = t / 12, c8 = t - r * 12;
    int gr = row0 + r;
    u16x8 o = {};
    if (gr < nrows) {
      u16x8 self = hin8[(size_t)gr * 12 + c8];
      float acc[8];
#pragma unroll
      for (int k = 0; k < 8; k++) acc[k] = bf2f(self[k]);
      int s = start[gr], e = s + deg[gr];
      int j = s;
      for (; j + 4 <= e; j += 4) {
        int i0 = csr[j], i1 = csr[j + 1], i2 = csr[j + 2], i3 = csr[j + 3];
        u16x8 v0 = hin8[(size_t)i0 * 12 + c8];
        u16x8 v1 = hin8[(size_t)i1 * 12 + c8];
        u16x8 v2 = hin8[(size_t)i2 * 12 + c8];
        u16x8 v3 = hin8[(size_t)i3 * 12 + c8];
#pragma unroll
        for (int k = 0; k < 8; k++)
          acc[k] += (bf2f(v0[k]) + bf2f(v1[k])) + (bf2f(v2[k]) + bf2f(v3[k]));
      }
      for (; j < e; j++) {
        u16x8 v = hin8[(size_t)csr[j] * 12 + c8];
#pragma unroll
        for (int k = 0; k < 8; k++) acc[k] += bf2f(v[k]);
      }
#pragma unroll
      for (int k = 0; k < 8; k++) o[k] = f2bf(acc[k]);
    }
    *reinterpret_cast<u16x8*>(&A_lds[r * LDA + 8 * c8]) = o;
  }
  __syncthreads();

  const int lane = tid & 63;
  const int w = tid >> 6;     // wave id: rows [16w, 16w+16)
  const int nl = lane & 15;   // frag row (A) / col (B,D)
  const int q = lane >> 4;    // k-quarter
  const int arow = 16 * w + nl;

  bfrag8 afrag[3];
#pragma unroll
  for (int s = 0; s < 3; s++)
    afrag[s] = *reinterpret_cast<const bfrag8*>(&A_lds[arow * LDA + 32 * s + 8 * q]);

  // GEMM1 -> relu -> Z (bf16) into this wave's own A stripe (no barrier needed)
#pragma unroll
  for (int cb = 0; cb < 6; cb++) {
    f32x4 acc = {0.f, 0.f, 0.f, 0.f};
#pragma unroll
    for (int s = 0; s < 3; s++) {
      bfrag8 bfr = *reinterpret_cast<const bfrag8*>(
          &W1_lds[(16 * cb + nl) * LDA + 32 * s + 8 * q]);
      acc = __builtin_amdgcn_mfma_f32_16x16x32_bf16(afrag[s], bfr, acc, 0, 0, 0);
    }
    float b = B1[16 * cb + nl];
#pragma unroll
    for (int i = 0; i < 4; i++) {
      int m = 16 * w + 4 * q + i;
      A_lds[m * LDA + 16 * cb + nl] = f2bf(fmaxf(acc[i] + b, 0.f));
    }
  }

  bfrag8 zfrag[3];
#pragma unroll
  for (int s = 0; s < 3; s++)
    zfrag[s] = *reinterpret_cast<const bfrag8*>(&A_lds[arow * LDA + 32 * s + 8 * q]);

  float oacc[40];  // LAST only: per-lane partial out[i][c], static-indexed
#pragma unroll
  for (int t2 = 0; t2 < 40; t2++) oacc[t2] = 0.f;

#pragma unroll
  for (int cb = 0; cb < 6; cb++) {
    f32x4 acc = {0.f, 0.f, 0.f, 0.f};
#pragma unroll
    for (int s = 0; s < 3; s++) {
      bfrag8 bfr = *reinterpret_cast<const bfrag8*>(
          &W2_lds[(16 * cb + nl) * LDA + 32 * s + 8 * q]);
      acc = __builtin_amdgcn_mfma_f32_16x16x32_bf16(zfrag[s], bfr, acc, 0, 0, 0);
    }
    float b = B2[16 * cb + nl];
#pragma unroll
    for (int i = 0; i < 4; i++) {
      float hv = fmaxf(acc[i] + b, 0.f);
      if (!LAST) {
        int m = 16 * w + 4 * q + i;
        int gr = row0 + m;
        if (gr < nrows) out[(size_t)gr * 96 + 16 * cb + nl] = f2bf(hv);
      } else {
#pragma unroll
        for (int c = 0; c < 10; c++)
          oacc[i * 10 + c] += hv * Wc[(16 * cb + nl) * 10 + c];
      }
    }
  }

  if (LAST) {
    // reduce over the 16 nl-lanes within each q-group
#pragma unroll
    for (int m = 1; m < 16; m <<= 1) {
#pragma unroll
      for (int t2 = 0; t2 < 40; t2++) oacc[t2] += __shfl_xor(oacc[t2], m, 64);
    }
#pragma unroll
    for (int i = 0; i < 4; i++) {
      int gr = row0 + 16 * w + 4 * q + i;
      if (gr < nrows && nl < 10) {
        float v = 0.f;
#pragma unroll
        for (int c = 0; c < 10; c++)
          if (nl == c) v = oacc[i * 10 + c];
        outf[(size_t)gr * 10 + nl] = v + Bc[nl];
      }
    }
  }
}

extern "C" void kernel_launch(void* const* d_in, const int* in_sizes, int n_in,
                              void* d_out, int out_size, void* d_ws, size_t ws_size,
                              hipStream_t stream) {
  const float* x  = (const float*)d_in[0];
  const int*   ei = (const int*)d_in[1];
  const float* W1 = (const float*)d_in[2];
  const float* B1 = (const float*)d_in[3];
  const float* W2 = (const float*)d_in[4];
  const float* B2 = (const float*)d_in[5];
  const float* Wc = (const float*)d_in[6];
  const float* Bc = (const float*)d_in[7];
  float* out = (float*)d_out;

  const int N = in_sizes[0] / 96;
  const int E = in_sizes[1] / 2;
  const int* src = ei;       // edge_index[0]
  const int* dst = ei + E;   // edge_index[1]

  unsigned short* hbuf = (unsigned short*)d_ws;          // N*96 bf16
  unsigned short* hbuf2 = hbuf + (size_t)N * 96;         // N*96 bf16 (ping-pong)
  int* start   = (int*)(hbuf2 + (size_t)N * 96);
  int* cursor  = start + N;                 // dead after fill -> reused for wt
  int* deg     = cursor + N;
  int* counter = deg + N;
  int* csr     = counter + 1;
  unsigned short* wt = (unsigned short*)cursor;  // 6*9216 u16 = 110.6 KB <= N*4 B

  hipMemsetAsync(deg, 0, (size_t)(N + 1) * sizeof(int), stream);  // deg + counter
  hist_kernel<<<(E + TPB - 1) / TPB, TPB, 0, stream>>>(dst, deg, E);
  assign_kernel<<<(N + TPB - 1) / TPB, TPB, 0, stream>>>(deg, start, cursor, counter, N);
  fill_kernel<<<(E / 2 + TPB - 1) / TPB, TPB, 0, stream>>>(src, dst, cursor, csr, E);

  const int total8 = N * 12;
  prep_kernel<<<(6 * 9216 + total8 + TPB - 1) / TPB, TPB, 0, stream>>>(
      W1, W2, wt, (const float4*)x, (u16x8*)hbuf, total8);

  const int nblk = (N + 63) / 64;
  unsigned short* hin = hbuf;
  unsigned short* hout = hbuf2;
  for (int l = 0; l < 3; l++) {
    const unsigned short* wt1 = wt + (size_t)(l * 2) * 9216;
    const unsigned short* wt2 = wt + (size_t)(l * 2 + 1) * 9216;
    const float* b1 = B1 + (size_t)l * 96;
    const float* b2 = B2 + (size_t)l * 96;
    if (l < 2) {
      mlp_fused_kernel<false><<<nblk, TPB, 0, stream>>>(
          (const u16x8*)hin, start, deg, csr, wt1, wt2, b1, b2, hout,
          Wc, Bc, out, N);
      unsigned short* tmp = hin; hin = hout; hout = tmp;
    } else {
      mlp_fused_kernel<true><<<nblk, TPB, 0, stream>>>(
          (const u16x8*)hin, start, deg, csr, wt1, wt2, b1, b2, hout,
          Wc, Bc, out, N);
    }
  }
}

// Round 9
// 236.342 us; speedup vs baseline: 1.1546x; 1.1546x over previous
//
#include <hip/hip_runtime.h>

// StackedGIN: L=3 layers of { agg = h + scatter_sum(h[src] -> dst);
//   h = relu( relu(agg@W1+B1) @ W2 + B2 ) }, then out = h@Wc + Bc.
// N=50000, E=800000, D=96, C=10.
//
// R1: float4 gather, unroll x4.  R2: wave-scan slot assignment.
// R3: MLP via bf16 MFMA.         R4: h/agg stored bf16 (gather halved).
// R5: prep fuse; classifier fused into layer-3 MLP epilogue.
// R6: plain-dispatch CSR build (coop grid.sync 5x slower on scatter phases).
// R7 FAILED (reverted): agg fused into MLP -> grid capped at 782 blocks,
//     12 waves/CU, latency-bound gather 2.4x slower. Keep split kernels.
// R8: (a) csr as u16 (src<65536) -> fill dirty-line count halved;
//     (b) prep merged into hist (disjoint ranges; hist is atomic-bound).
// ws layout: hbuf(N*96 bf16) | aggbuf(N*96 bf16) | start(N) | cursor(N) |
//            deg(N) | counter(1) | csr16(E u16) | wt(6*9216 u16)

#define TPB 256
#define LDA 104  // bf16 elems per LDS row: 96 + 8 pad

typedef __attribute__((ext_vector_type(8))) short bfrag8;
typedef __attribute__((ext_vector_type(8))) unsigned short u16x8;
typedef __attribute__((ext_vector_type(4))) float f32x4;

__device__ inline unsigned short f2bf(float x) {  // RNE f32 -> bf16 bits
  unsigned int u = __float_as_uint(x);
  unsigned int r = u + 0x7FFFu + ((u >> 16) & 1u);
  return (unsigned short)(r >> 16);
}
__device__ inline float bf2f(unsigned short u) {
  return __uint_as_float(((unsigned int)u) << 16);
}

// threads [0,E): histogram of dst. threads [E, E+wjobs+total8): weight
// transpose->bf16 and x->bf16 (independent streaming work rides along the
// atomic-bound histogram).
__global__ __launch_bounds__(TPB) void histprep_kernel(
    const int* __restrict__ dst, int* __restrict__ deg, int E,
    const float* __restrict__ W1, const float* __restrict__ W2,
    unsigned short* __restrict__ wt,
    const float4* __restrict__ x4, u16x8* __restrict__ h8, int total8) {
  int t = blockIdx.x * TPB + threadIdx.x;
  if (t < E) {
    atomicAdd(&deg[dst[t]], 1);
    return;
  }
  t -= E;
  const int wjobs = 6 * 9216;
  if (t < wjobs) {
    int mat = t / 9216, idx = t - mat * 9216;
    int l = mat >> 1, which = mat & 1;
    int k = idx / 96, n = idx - k * 96;
    const float* src = (which ? W2 : W1) + (size_t)l * 9216;
    wt[(size_t)mat * 9216 + n * 96 + k] = f2bf(src[k * 96 + n]);
  } else {
    int u = t - wjobs;
    if (u < total8) {
      float4 a = x4[2 * u], b = x4[2 * u + 1];
      u16x8 o;
      o[0] = f2bf(a.x); o[1] = f2bf(a.y); o[2] = f2bf(a.z); o[3] = f2bf(a.w);
      o[4] = f2bf(b.x); o[5] = f2bf(b.y); o[6] = f2bf(b.z); o[7] = f2bf(b.w);
      h8[u] = o;
    }
  }
}

// start[i] = running sum of deg in wave-chunked order (order irrelevant).
__global__ __launch_bounds__(TPB) void assign_kernel(const int* __restrict__ deg,
                                                     int* __restrict__ start,
                                                     int* __restrict__ cursor,
                                                     int* __restrict__ counter, int n) {
  int i = blockIdx.x * TPB + threadIdx.x;
  int d = (i < n) ? deg[i] : 0;
  int lane = threadIdx.x & 63;
  int incl = d;
#pragma unroll
  for (int off = 1; off < 64; off <<= 1) {
    int v = __shfl_up(incl, off, 64);
    if (lane >= off) incl += v;
  }
  int waveTotal = __shfl(incl, 63, 64);
  int base = 0;
  if (lane == 63) base = atomicAdd(counter, waveTotal);
  base = __shfl(base, 63, 64);
  int st = base + incl - d;
  if (i < n) { start[i] = st; cursor[i] = st; }
}

// fill: 2 edges per thread; csr entries are u16 (src < 65536).
__global__ __launch_bounds__(TPB) void fill_kernel(const int* __restrict__ src,
                                                   const int* __restrict__ dst,
                                                   int* __restrict__ cursor,
                                                   unsigned short* __restrict__ csr16,
                                                   int E) {
  int t = blockIdx.x * TPB + threadIdx.x;
  int e0 = 2 * t, e1 = 2 * t + 1;
  if (e1 < E) {
    int d0 = dst[e0], d1 = dst[e1];
    int s0 = src[e0], s1 = src[e1];
    int slot0 = atomicAdd(&cursor[d0], 1);
    int slot1 = atomicAdd(&cursor[d1], 1);
    csr16[slot0] = (unsigned short)s0;
    csr16[slot1] = (unsigned short)s1;
  } else if (e0 < E) {
    int d0 = dst[e0];
    int slot0 = atomicAdd(&cursor[d0], 1);
    csr16[slot0] = (unsigned short)src[e0];
  }
}

// agg[i][c8] = h[i][c8] + sum_{j in row i} h[csr[j]][c8]; bf16 in/out,
// f32 accumulate. 12 threads/node (96/8), unroll x4 for MLP.
__global__ __launch_bounds__(TPB) void aggb_kernel(const u16x8* __restrict__ hin8,
                                                   u16x8* __restrict__ hout8,
                                                   const int* __restrict__ start,
                                                   const int* __restrict__ deg,
                                                   const unsigned short* __restrict__ csr16,
                                                   int n) {
  int t = blockIdx.x * TPB + threadIdx.x;
  if (t >= n * 12) return;
  int i = t / 12;
  int f = t - i * 12;
  u16x8 self = hin8[t];
  float acc[8];
#pragma unroll
  for (int k = 0; k < 8; k++) acc[k] = bf2f(self[k]);
  int s = start[i], e = s + deg[i];
  int j = s;
  for (; j + 4 <= e; j += 4) {
    int i0 = csr16[j], i1 = csr16[j + 1], i2 = csr16[j + 2], i3 = csr16[j + 3];
    u16x8 v0 = hin8[(size_t)i0 * 12 + f];
    u16x8 v1 = hin8[(size_t)i1 * 12 + f];
    u16x8 v2 = hin8[(size_t)i2 * 12 + f];
    u16x8 v3 = hin8[(size_t)i3 * 12 + f];
#pragma unroll
    for (int k = 0; k < 8; k++)
      acc[k] += (bf2f(v0[k]) + bf2f(v1[k])) + (bf2f(v2[k]) + bf2f(v3[k]));
  }
  for (; j < e; j++) {
    u16x8 v = hin8[(size_t)csr16[j] * 12 + f];
#pragma unroll
    for (int k = 0; k < 8; k++) acc[k] += bf2f(v[k]);
  }
  u16x8 o;
#pragma unroll
  for (int k = 0; k < 8; k++) o[k] = f2bf(acc[k]);
  hout8[t] = o;
}

// h = relu( relu(agg@W1+B1) @ W2 + B2 ); LAST also computes out = h@Wc + Bc
// (h never stored for the last layer). Block: 64 rows, 4 waves x 16-row stripe.
template <bool LAST>
__global__ __launch_bounds__(TPB) void mlp_mfma_kernel(
    const u16x8* __restrict__ in8, const unsigned short* __restrict__ wt1,
    const unsigned short* __restrict__ wt2, const float* __restrict__ B1,
    const float* __restrict__ B2, unsigned short* __restrict__ out,
    const float* __restrict__ Wc, const float* __restrict__ Bc,
    float* __restrict__ outf, int nrows) {
  __shared__ unsigned short A_lds[64 * LDA];   // A tile, later Z tile
  __shared__ unsigned short W1_lds[96 * LDA];
  __shared__ unsigned short W2_lds[96 * LDA];
  const int tid = threadIdx.x;
  const int row0 = blockIdx.x * 64;

  // stage A (already bf16), rows [row0, row0+64)
  for (int t = tid; t < 64 * 12; t += TPB) {
    int r = t / 12, c8 = t - r * 12;
    int gr = row0 + r;
    u16x8 v = {};
    if (gr < nrows) v = in8[(size_t)gr * 12 + c8];
    *reinterpret_cast<u16x8*>(&A_lds[r * LDA + 8 * c8]) = v;
  }
  // stage Wt1, Wt2 (bf16, 16B chunks)
  for (int t = tid; t < 2 * 1152; t += TPB) {
    int which = t / 1152, idx = t - which * 1152;
    int n = idx / 12, c8 = idx - n * 12;
    const unsigned short* src = (which ? wt2 : wt1) + n * 96 + 8 * c8;
    bfrag8 v = *reinterpret_cast<const bfrag8*>(src);
    unsigned short* dp = (which ? W2_lds : W1_lds) + n * LDA + 8 * c8;
    *reinterpret_cast<bfrag8*>(dp) = v;
  }
  __syncthreads();

  const int lane = tid & 63;
  const int w = tid >> 6;     // wave id: rows [16w, 16w+16)
  const int nl = lane & 15;   // frag row (A) / col (B,D)
  const int q = lane >> 4;    // k-quarter
  const int arow = 16 * w + nl;

  bfrag8 afrag[3];
#pragma unroll
  for (int s = 0; s < 3; s++)
    afrag[s] = *reinterpret_cast<const bfrag8*>(&A_lds[arow * LDA + 32 * s + 8 * q]);

  // GEMM1 -> relu -> Z (bf16) into this wave's own A stripe (no barrier needed)
#pragma unroll
  for (int cb = 0; cb < 6; cb++) {
    f32x4 acc = {0.f, 0.f, 0.f, 0.f};
#pragma unroll
    for (int s = 0; s < 3; s++) {
      bfrag8 bfr = *reinterpret_cast<const bfrag8*>(
          &W1_lds[(16 * cb + nl) * LDA + 32 * s + 8 * q]);
      acc = __builtin_amdgcn_mfma_f32_16x16x32_bf16(afrag[s], bfr, acc, 0, 0, 0);
    }
    float b = B1[16 * cb + nl];
#pragma unroll
    for (int i = 0; i < 4; i++) {
      int m = 16 * w + 4 * q + i;
      A_lds[m * LDA + 16 * cb + nl] = f2bf(fmaxf(acc[i] + b, 0.f));
    }
  }

  bfrag8 zfrag[3];
#pragma unroll
  for (int s = 0; s < 3; s++)
    zfrag[s] = *reinterpret_cast<const bfrag8*>(&A_lds[arow * LDA + 32 * s + 8 * q]);

  float oacc[40];  // LAST only: per-lane partial out[i][c], static-indexed
#pragma unroll
  for (int t2 = 0; t2 < 40; t2++) oacc[t2] = 0.f;

#pragma unroll
  for (int cb = 0; cb < 6; cb++) {
    f32x4 acc = {0.f, 0.f, 0.f, 0.f};
#pragma unroll
    for (int s = 0; s < 3; s++) {
      bfrag8 bfr = *reinterpret_cast<const bfrag8*>(
          &W2_lds[(16 * cb + nl) * LDA + 32 * s + 8 * q]);
      acc = __builtin_amdgcn_mfma_f32_16x16x32_bf16(zfrag[s], bfr, acc, 0, 0, 0);
    }
    float b = B2[16 * cb + nl];
#pragma unroll
    for (int i = 0; i < 4; i++) {
      float hv = fmaxf(acc[i] + b, 0.f);
      if (!LAST) {
        int m = 16 * w + 4 * q + i;
        int gr = row0 + m;
        if (gr < nrows) out[(size_t)gr * 96 + 16 * cb + nl] = f2bf(hv);
      } else {
#pragma unroll
        for (int c = 0; c < 10; c++)
          oacc[i * 10 + c] += hv * Wc[(16 * cb + nl) * 10 + c];
      }
    }
  }

  if (LAST) {
    // reduce over the 16 nl-lanes within each q-group
#pragma unroll
    for (int m = 1; m < 16; m <<= 1) {
#pragma unroll
      for (int t2 = 0; t2 < 40; t2++) oacc[t2] += __shfl_xor(oacc[t2], m, 64);
    }
#pragma unroll
    for (int i = 0; i < 4; i++) {
      int gr = row0 + 16 * w + 4 * q + i;
      if (gr < nrows && nl < 10) {
        float v = 0.f;
#pragma unroll
        for (int c = 0; c < 10; c++)
          if (nl == c) v = oacc[i * 10 + c];
        outf[(size_t)gr * 10 + nl] = v + Bc[nl];
      }
    }
  }
}

extern "C" void kernel_launch(void* const* d_in, const int* in_sizes, int n_in,
                              void* d_out, int out_size, void* d_ws, size_t ws_size,
                              hipStream_t stream) {
  const float* x  = (const float*)d_in[0];
  const int*   ei = (const int*)d_in[1];
  const float* W1 = (const float*)d_in[2];
  const float* B1 = (const float*)d_in[3];
  const float* W2 = (const float*)d_in[4];
  const float* B2 = (const float*)d_in[5];
  const float* Wc = (const float*)d_in[6];
  const float* Bc = (const float*)d_in[7];
  float* out = (float*)d_out;

  const int N = in_sizes[0] / 96;
  const int E = in_sizes[1] / 2;
  const int* src = ei;       // edge_index[0]
  const int* dst = ei + E;   // edge_index[1]

  unsigned short* hbuf   = (unsigned short*)d_ws;        // N*96 bf16
  unsigned short* aggbuf = hbuf + (size_t)N * 96;        // N*96 bf16
  int* start   = (int*)(aggbuf + (size_t)N * 96);
  int* cursor  = start + N;
  int* deg     = cursor + N;
  int* counter = deg + N;
  unsigned short* csr16 = (unsigned short*)(counter + 1);  // E u16
  unsigned short* wt    = csr16 + (size_t)E;               // 6*9216 u16

  hipMemsetAsync(deg, 0, (size_t)(N + 1) * sizeof(int), stream);  // deg + counter

  const int total8 = N * 12;
  const int histprep_jobs = E + 6 * 9216 + total8;
  histprep_kernel<<<(histprep_jobs + TPB - 1) / TPB, TPB, 0, stream>>>(
      dst, deg, E, W1, W2, wt, (const float4*)x, (u16x8*)hbuf, total8);

  assign_kernel<<<(N + TPB - 1) / TPB, TPB, 0, stream>>>(deg, start, cursor, counter, N);
  fill_kernel<<<(E / 2 + TPB - 1) / TPB, TPB, 0, stream>>>(src, dst, cursor, csr16, E);

  for (int l = 0; l < 3; l++) {
    aggb_kernel<<<((N * 12) + TPB - 1) / TPB, TPB, 0, stream>>>(
        (const u16x8*)hbuf, (u16x8*)aggbuf, start, deg, csr16, N);
    const unsigned short* wt1 = wt + (size_t)(l * 2) * 9216;
    const unsigned short* wt2 = wt + (size_t)(l * 2 + 1) * 9216;
    const float* b1 = B1 + (size_t)l * 96;
    const float* b2 = B2 + (size_t)l * 96;
    if (l < 2)
      mlp_mfma_kernel<false><<<(N + 63) / 64, TPB, 0, stream>>>(
          (const u16x8*)aggbuf, wt1, wt2, b1, b2, hbuf, Wc, Bc, out, N);
    else
      mlp_mfma_kernel<true><<<(N + 63) / 64, TPB, 0, stream>>>(
          (const u16x8*)aggbuf, wt1, wt2, b1, b2, hbuf, Wc, Bc, out, N);
  }
}

// Round 10
// 234.862 us; speedup vs baseline: 1.1619x; 1.0063x over previous
//
#include <hip/hip_runtime.h>

// StackedGIN: L=3 layers of { agg = h + scatter_sum(h[src] -> dst);
//   h = relu( relu(agg@W1+B1) @ W2 + B2 ) }, then out = h@Wc + Bc.
// N=50000, E=800000, D=96, C=10.
//
// R1: float4 gather, unroll x4.  R2: wave-scan slot assignment.
// R3: MLP via bf16 MFMA.         R4: h/agg stored bf16 (gather halved).
// R5: prep fuse; classifier fused into layer-3 MLP epilogue.
// R6: plain-dispatch CSR build (coop grid.sync 5x slower on scatter phases).
// R7 FAILED (reverted): agg fused into MLP capped gather occupancy.
// R8: csr as u16; prep merged into hist.
// R9: hipMemsetAsync(deg) -> custom zero_kernel. rocclr fillBufferAligned
//     ran at 8.6% occupancy / ~43us EVERY call (hidden below top-5 cutoff
//     since R0). 200KB zero should be ~2us.
// ws layout: hbuf(N*96 bf16) | aggbuf(N*96 bf16) | start(N) | cursor(N) |
//            deg(N) | counter(1) | csr16(E u16) | wt(6*9216 u16)

#define TPB 256
#define LDA 104  // bf16 elems per LDS row: 96 + 8 pad

typedef __attribute__((ext_vector_type(8))) short bfrag8;
typedef __attribute__((ext_vector_type(8))) unsigned short u16x8;
typedef __attribute__((ext_vector_type(4))) float f32x4;

__device__ inline unsigned short f2bf(float x) {  // RNE f32 -> bf16 bits
  unsigned int u = __float_as_uint(x);
  unsigned int r = u + 0x7FFFu + ((u >> 16) & 1u);
  return (unsigned short)(r >> 16);
}
__device__ inline float bf2f(unsigned short u) {
  return __uint_as_float(((unsigned int)u) << 16);
}

__global__ __launch_bounds__(TPB) void zero_kernel(int* __restrict__ p, int n) {
  int i = blockIdx.x * TPB + threadIdx.x;
  if (i < n) p[i] = 0;
}

// threads [0,E): histogram of dst. threads [E, E+wjobs+total8): weight
// transpose->bf16 and x->bf16 (independent streaming work rides along the
// atomic-bound histogram).
__global__ __launch_bounds__(TPB) void histprep_kernel(
    const int* __restrict__ dst, int* __restrict__ deg, int E,
    const float* __restrict__ W1, const float* __restrict__ W2,
    unsigned short* __restrict__ wt,
    const float4* __restrict__ x4, u16x8* __restrict__ h8, int total8) {
  int t = blockIdx.x * TPB + threadIdx.x;
  if (t < E) {
    atomicAdd(&deg[dst[t]], 1);
    return;
  }
  t -= E;
  const int wjobs = 6 * 9216;
  if (t < wjobs) {
    int mat = t / 9216, idx = t - mat * 9216;
    int l = mat >> 1, which = mat & 1;
    int k = idx / 96, n = idx - k * 96;
    const float* src = (which ? W2 : W1) + (size_t)l * 9216;
    wt[(size_t)mat * 9216 + n * 96 + k] = f2bf(src[k * 96 + n]);
  } else {
    int u = t - wjobs;
    if (u < total8) {
      float4 a = x4[2 * u], b = x4[2 * u + 1];
      u16x8 o;
      o[0] = f2bf(a.x); o[1] = f2bf(a.y); o[2] = f2bf(a.z); o[3] = f2bf(a.w);
      o[4] = f2bf(b.x); o[5] = f2bf(b.y); o[6] = f2bf(b.z); o[7] = f2bf(b.w);
      h8[u] = o;
    }
  }
}

// start[i] = running sum of deg in wave-chunked order (order irrelevant).
__global__ __launch_bounds__(TPB) void assign_kernel(const int* __restrict__ deg,
                                                     int* __restrict__ start,
                                                     int* __restrict__ cursor,
                                                     int* __restrict__ counter, int n) {
  int i = blockIdx.x * TPB + threadIdx.x;
  int d = (i < n) ? deg[i] : 0;
  int lane = threadIdx.x & 63;
  int incl = d;
#pragma unroll
  for (int off = 1; off < 64; off <<= 1) {
    int v = __shfl_up(incl, off, 64);
    if (lane >= off) incl += v;
  }
  int waveTotal = __shfl(incl, 63, 64);
  int base = 0;
  if (lane == 63) base = atomicAdd(counter, waveTotal);
  base = __shfl(base, 63, 64);
  int st = base + incl - d;
  if (i < n) { start[i] = st; cursor[i] = st; }
}

// fill: 2 edges per thread; csr entries are u16 (src < 65536).
__global__ __launch_bounds__(TPB) void fill_kernel(const int* __restrict__ src,
                                                   const int* __restrict__ dst,
                                                   int* __restrict__ cursor,
                                                   unsigned short* __restrict__ csr16,
                                                   int E) {
  int t = blockIdx.x * TPB + threadIdx.x;
  int e0 = 2 * t, e1 = 2 * t + 1;
  if (e1 < E) {
    int d0 = dst[e0], d1 = dst[e1];
    int s0 = src[e0], s1 = src[e1];
    int slot0 = atomicAdd(&cursor[d0], 1);
    int slot1 = atomicAdd(&cursor[d1], 1);
    csr16[slot0] = (unsigned short)s0;
    csr16[slot1] = (unsigned short)s1;
  } else if (e0 < E) {
    int d0 = dst[e0];
    int slot0 = atomicAdd(&cursor[d0], 1);
    csr16[slot0] = (unsigned short)src[e0];
  }
}

// agg[i][c8] = h[i][c8] + sum_{j in row i} h[csr[j]][c8]; bf16 in/out,
// f32 accumulate. 12 threads/node (96/8), unroll x4 for MLP.
__global__ __launch_bounds__(TPB) void aggb_kernel(const u16x8* __restrict__ hin8,
                                                   u16x8* __restrict__ hout8,
                                                   const int* __restrict__ start,
                                                   const int* __restrict__ deg,
                                                   const unsigned short* __restrict__ csr16,
                                                   int n) {
  int t = blockIdx.x * TPB + threadIdx.x;
  if (t >= n * 12) return;
  int i = t / 12;
  int f = t - i * 12;
  u16x8 self = hin8[t];
  float acc[8];
#pragma unroll
  for (int k = 0; k < 8; k++) acc[k] = bf2f(self[k]);
  int s = start[i], e = s + deg[i];
  int j = s;
  for (; j + 4 <= e; j += 4) {
    int i0 = csr16[j], i1 = csr16[j + 1], i2 = csr16[j + 2], i3 = csr16[j + 3];
    u16x8 v0 = hin8[(size_t)i0 * 12 + f];
    u16x8 v1 = hin8[(size_t)i1 * 12 + f];
    u16x8 v2 = hin8[(size_t)i2 * 12 + f];
    u16x8 v3 = hin8[(size_t)i3 * 12 + f];
#pragma unroll
    for (int k = 0; k < 8; k++)
      acc[k] += (bf2f(v0[k]) + bf2f(v1[k])) + (bf2f(v2[k]) + bf2f(v3[k]));
  }
  for (; j < e; j++) {
    u16x8 v = hin8[(size_t)csr16[j] * 12 + f];
#pragma unroll
    for (int k = 0; k < 8; k++) acc[k] += bf2f(v[k]);
  }
  u16x8 o;
#pragma unroll
  for (int k = 0; k < 8; k++) o[k] = f2bf(acc[k]);
  hout8[t] = o;
}

// h = relu( relu(agg@W1+B1) @ W2 + B2 ); LAST also computes out = h@Wc + Bc
// (h never stored for the last layer). Block: 64 rows, 4 waves x 16-row stripe.
template <bool LAST>
__global__ __launch_bounds__(TPB) void mlp_mfma_kernel(
    const u16x8* __restrict__ in8, const unsigned short* __restrict__ wt1,
    const unsigned short* __restrict__ wt2, const float* __restrict__ B1,
    const float* __restrict__ B2, unsigned short* __restrict__ out,
    const float* __restrict__ Wc, const float* __restrict__ Bc,
    float* __restrict__ outf, int nrows) {
  __shared__ unsigned short A_lds[64 * LDA];   // A tile, later Z tile
  __shared__ unsigned short W1_lds[96 * LDA];
  __shared__ unsigned short W2_lds[96 * LDA];
  const int tid = threadIdx.x;
  const int row0 = blockIdx.x * 64;

  // stage A (already bf16), rows [row0, row0+64)
  for (int t = tid; t < 64 * 12; t += TPB) {
    int r = t / 12, c8 = t - r * 12;
    int gr = row0 + r;
    u16x8 v = {};
    if (gr < nrows) v = in8[(size_t)gr * 12 + c8];
    *reinterpret_cast<u16x8*>(&A_lds[r * LDA + 8 * c8]) = v;
  }
  // stage Wt1, Wt2 (bf16, 16B chunks)
  for (int t = tid; t < 2 * 1152; t += TPB) {
    int which = t / 1152, idx = t - which * 1152;
    int n = idx / 12, c8 = idx - n * 12;
    const unsigned short* src = (which ? wt2 : wt1) + n * 96 + 8 * c8;
    bfrag8 v = *reinterpret_cast<const bfrag8*>(src);
    unsigned short* dp = (which ? W2_lds : W1_lds) + n * LDA + 8 * c8;
    *reinterpret_cast<bfrag8*>(dp) = v;
  }
  __syncthreads();

  const int lane = tid & 63;
  const int w = tid >> 6;     // wave id: rows [16w, 16w+16)
  const int nl = lane & 15;   // frag row (A) / col (B,D)
  const int q = lane >> 4;    // k-quarter
  const int arow = 16 * w + nl;

  bfrag8 afrag[3];
#pragma unroll
  for (int s = 0; s < 3; s++)
    afrag[s] = *reinterpret_cast<const bfrag8*>(&A_lds[arow * LDA + 32 * s + 8 * q]);

  // GEMM1 -> relu -> Z (bf16) into this wave's own A stripe (no barrier needed)
#pragma unroll
  for (int cb = 0; cb < 6; cb++) {
    f32x4 acc = {0.f, 0.f, 0.f, 0.f};
#pragma unroll
    for (int s = 0; s < 3; s++) {
      bfrag8 bfr = *reinterpret_cast<const bfrag8*>(
          &W1_lds[(16 * cb + nl) * LDA + 32 * s + 8 * q]);
      acc = __builtin_amdgcn_mfma_f32_16x16x32_bf16(afrag[s], bfr, acc, 0, 0, 0);
    }
    float b = B1[16 * cb + nl];
#pragma unroll
    for (int i = 0; i < 4; i++) {
      int m = 16 * w + 4 * q + i;
      A_lds[m * LDA + 16 * cb + nl] = f2bf(fmaxf(acc[i] + b, 0.f));
    }
  }

  bfrag8 zfrag[3];
#pragma unroll
  for (int s = 0; s < 3; s++)
    zfrag[s] = *reinterpret_cast<const bfrag8*>(&A_lds[arow * LDA + 32 * s + 8 * q]);

  float oacc[40];  // LAST only: per-lane partial out[i][c], static-indexed
#pragma unroll
  for (int t2 = 0; t2 < 40; t2++) oacc[t2] = 0.f;

#pragma unroll
  for (int cb = 0; cb < 6; cb++) {
    f32x4 acc = {0.f, 0.f, 0.f, 0.f};
#pragma unroll
    for (int s = 0; s < 3; s++) {
      bfrag8 bfr = *reinterpret_cast<const bfrag8*>(
          &W2_lds[(16 * cb + nl) * LDA + 32 * s + 8 * q]);
      acc = __builtin_amdgcn_mfma_f32_16x16x32_bf16(zfrag[s], bfr, acc, 0, 0, 0);
    }
    float b = B2[16 * cb + nl];
#pragma unroll
    for (int i = 0; i < 4; i++) {
      float hv = fmaxf(acc[i] + b, 0.f);
      if (!LAST) {
        int m = 16 * w + 4 * q + i;
        int gr = row0 + m;
        if (gr < nrows) out[(size_t)gr * 96 + 16 * cb + nl] = f2bf(hv);
      } else {
#pragma unroll
        for (int c = 0; c < 10; c++)
          oacc[i * 10 + c] += hv * Wc[(16 * cb + nl) * 10 + c];
      }
    }
  }

  if (LAST) {
    // reduce over the 16 nl-lanes within each q-group
#pragma unroll
    for (int m = 1; m < 16; m <<= 1) {
#pragma unroll
      for (int t2 = 0; t2 < 40; t2++) oacc[t2] += __shfl_xor(oacc[t2], m, 64);
    }
#pragma unroll
    for (int i = 0; i < 4; i++) {
      int gr = row0 + 16 * w + 4 * q + i;
      if (gr < nrows && nl < 10) {
        float v = 0.f;
#pragma unroll
        for (int c = 0; c < 10; c++)
          if (nl == c) v = oacc[i * 10 + c];
        outf[(size_t)gr * 10 + nl] = v + Bc[nl];
      }
    }
  }
}

extern "C" void kernel_launch(void* const* d_in, const int* in_sizes, int n_in,
                              void* d_out, int out_size, void* d_ws, size_t ws_size,
                              hipStream_t stream) {
  const float* x  = (const float*)d_in[0];
  const int*   ei = (const int*)d_in[1];
  const float* W1 = (const float*)d_in[2];
  const float* B1 = (const float*)d_in[3];
  const float* W2 = (const float*)d_in[4];
  const float* B2 = (const float*)d_in[5];
  const float* Wc = (const float*)d_in[6];
  const float* Bc = (const float*)d_in[7];
  float* out = (float*)d_out;

  const int N = in_sizes[0] / 96;
  const int E = in_sizes[1] / 2;
  const int* src = ei;       // edge_index[0]
  const int* dst = ei + E;   // edge_index[1]

  unsigned short* hbuf   = (unsigned short*)d_ws;        // N*96 bf16
  unsigned short* aggbuf = hbuf + (size_t)N * 96;        // N*96 bf16
  int* start   = (int*)(aggbuf + (size_t)N * 96);
  int* cursor  = start + N;
  int* deg     = cursor + N;
  int* counter = deg + N;
  unsigned short* csr16 = (unsigned short*)(counter + 1);  // E u16
  unsigned short* wt    = csr16 + (size_t)E;               // 6*9216 u16

  // deg..counter is contiguous (N+1 ints): zero with our own kernel
  // (rocclr fillBufferAligned was 43us at 8.6% occupancy).
  zero_kernel<<<(N + 1 + TPB - 1) / TPB, TPB, 0, stream>>>(deg, N + 1);

  const int total8 = N * 12;
  const int histprep_jobs = E + 6 * 9216 + total8;
  histprep_kernel<<<(histprep_jobs + TPB - 1) / TPB, TPB, 0, stream>>>(
      dst, deg, E, W1, W2, wt, (const float4*)x, (u16x8*)hbuf, total8);

  assign_kernel<<<(N + TPB - 1) / TPB, TPB, 0, stream>>>(deg, start, cursor, counter, N);
  fill_kernel<<<(E / 2 + TPB - 1) / TPB, TPB, 0, stream>>>(src, dst, cursor, csr16, E);

  for (int l = 0; l < 3; l++) {
    aggb_kernel<<<((N * 12) + TPB - 1) / TPB, TPB, 0, stream>>>(
        (const u16x8*)hbuf, (u16x8*)aggbuf, start, deg, csr16, N);
    const unsigned short* wt1 = wt + (size_t)(l * 2) * 9216;
    const unsigned short* wt2 = wt + (size_t)(l * 2 + 1) * 9216;
    const float* b1 = B1 + (size_t)l * 96;
    const float* b2 = B2 + (size_t)l * 96;
    if (l < 2)
      mlp_mfma_kernel<false><<<(N + 63) / 64, TPB, 0, stream>>>(
          (const u16x8*)aggbuf, wt1, wt2, b1, b2, hbuf, Wc, Bc, out, N);
    else
      mlp_mfma_kernel<true><<<(N + 63) / 64, TPB, 0, stream>>>(
          (const u16x8*)aggbuf, wt1, wt2, b1, b2, hbuf, Wc, Bc, out, N);
  }
}